// Round 13
// baseline (156.112 us; speedup 1.0000x reference)
//
#include <hip/hip_runtime.h>
#include <math.h>

// b=4,n=2048 -> 8192 rows; d=1024; h=8; e=16; cs=2048. Output int32 [8192,8].
// argmax_c q.cbn_c == argmax_c ((x.W - mu*colsum(W)) . cbn_c): LN 1/sigma and
// q-norm are positive per-(row,head) scalars -> cancel. Codebook normalized fp64.
//
// MFMA path (verified R7/R10): fp32 operands split into 3 bf16 parts h,m,l
// (8+8+8 >= 24 mantissa bits; bf16 exp = fp32 -> no subnormal flush).
// v_p*v_c ~= hh + hm+mh + hl+mm+lh via 3 K=32 bf16 MFMAs, quad-packed:
// quads 0,1 carry part-A of the pair, quads 2,3 part-B. Dropped ml/lm/ll
// ~2^-25 rel. Frag-major B layouts (R9/R10).
//
// R13: proj column-split: block = 16 rows x 4 heads x full K, grid 1024
// (4 blocks/CU; R12's 512 was grid-capped at 2). x read twice (+5us HBM),
// occupancy ceiling 50%->100%.

typedef short bf16x8 __attribute__((ext_vector_type(8)));
typedef float f32x4 __attribute__((ext_vector_type(4)));

__device__ __forceinline__ void stage16(const float* g, float* lds_base) {
  __builtin_amdgcn_global_load_lds(
      (const __attribute__((address_space(1))) void*)g,
      (__attribute__((address_space(3))) void*)lds_base, 16, 0, 0);
}

__device__ __forceinline__ unsigned short f2bf(float f) {
  unsigned u = __builtin_bit_cast(unsigned, f);
  unsigned r = (u + 0x7FFFu + ((u >> 16) & 1u)) >> 16;   // RNE
  return (unsigned short)r;
}
__device__ __forceinline__ float bf2f(unsigned short b) {
  return __builtin_bit_cast(float, (unsigned)b << 16);
}
__device__ __forceinline__ void split3(float v, unsigned short& h,
                                       unsigned short& m, unsigned short& l) {
  h = f2bf(v);
  float r = v - bf2f(h);
  m = f2bf(r);
  float r2 = r - bf2f(m);
  l = f2bf(r2);
}

// ---------------- K1: fused prep: cbnorm | colsum | wsplit ------------------
// grid 136: [0,64) cbnorm -> cfrag [h][tile][p][n][oct][j] (1.5MB);
// [64,72) colsum -> csum[128]; [72,136) wsplit -> wfrag [dg][c][p][n][oct][j].
__global__ __launch_bounds__(256) void k_prep(const float* __restrict__ cb,
                                              const float* __restrict__ W,
                                              unsigned short* __restrict__ cfrag,
                                              float* __restrict__ csum,
                                              unsigned short* __restrict__ wfrag) {
  __shared__ float red[16][17];
  const int bid = blockIdx.x;
  const int t = threadIdx.x;
  if (bid < 64) {            // ---- cbnorm (fp64 normalize + bf16 3-split)
    int v = bid * 256 + t;
    int h = v >> 11, c = v & 2047, tl = c >> 4, n = c & 15;
    const float4* p = (const float4*)(cb + (size_t)v * 16);
    float4 q0 = p[0], q1 = p[1], q2 = p[2], q3 = p[3];
    float f[16] = {q0.x,q0.y,q0.z,q0.w, q1.x,q1.y,q1.z,q1.w,
                   q2.x,q2.y,q2.z,q2.w, q3.x,q3.y,q3.z,q3.w};
    double s = 0.0;
#pragma unroll
    for (int i = 0; i < 16; ++i) s += (double)f[i] * (double)f[i];
    double inv = 1.0 / sqrt(s + 1e-12);
    __attribute__((aligned(16))) unsigned short vp[3][16];
#pragma unroll
    for (int i = 0; i < 16; ++i)
      split3((float)((double)f[i] * inv), vp[0][i], vp[1][i], vp[2][i]);
#pragma unroll
    for (int pp = 0; pp < 3; ++pp) {
      size_t base = ((((size_t)h * 128 + tl) * 3 + pp) * 16 + n) * 16;
      ((bf16x8*)(cfrag + base))[0] = ((bf16x8*)vp[pp])[0];
      ((bf16x8*)(cfrag + base))[1] = ((bf16x8*)vp[pp])[1];
    }
  } else if (bid < 72) {     // ---- colsum
    int h = bid - 64;
    int e = t & 15, part = t >> 4;
    const float* base = W + h * 16384 + e;
    float s = 0.f;
    int d0 = part * 64;
    for (int i = 0; i < 64; ++i) s += base[(d0 + i) * 16];
    red[e][part] = s;
    __syncthreads();
    if (t < 16) {
      float tt = 0.f;
#pragma unroll
      for (int p = 0; p < 16; ++p) tt += red[t][p];
      csum[h * 16 + t] = tt;
    }
  } else {                   // ---- wsplit
    int id = (bid - 72) * 256 + t;
    int o = id & 1, n = (id >> 1) & 15, c = (id >> 5) & 7, dg = id >> 8;
    __attribute__((aligned(16))) unsigned short vp[3][8];
#pragma unroll
    for (int j = 0; j < 8; ++j) {
      float v = W[c * 16384 + (dg * 16 + o * 8 + j) * 16 + n];
      split3(v, vp[0][j], vp[1][j], vp[2][j]);
    }
#pragma unroll
    for (int pp = 0; pp < 3; ++pp) {
      size_t base = ((((size_t)dg * 8 + c) * 3 + pp) * 16 + n) * 16 + o * 8;
      *(bf16x8*)(wfrag + base) = *(bf16x8*)vp[pp];
    }
  }
}

// ---------------- K3: fused projection (full K, column-split) ---------------
// Grid (512 rowgroups, 2 head-halves) x 512 threads = 1024 blocks (4/CU).
// Block = 16 rows x 4 heads x K=1024; wave w covers d-groups [w*8, w*8+8).
// Wave-pair reduce (4-7 dump, 0-3 add), mu from fused row-sums (computed
// identically by both head-halves - free), csum correction, split3, direct
// ph/pm/pl emission.
__global__ __launch_bounds__(512) void k_proj(const float* __restrict__ x,
                                              const unsigned short* __restrict__ wfrag,
                                              const float* __restrict__ csum,
                                              unsigned short* __restrict__ ph,
                                              unsigned short* __restrict__ pm,
                                              unsigned short* __restrict__ pl) {
  __shared__ float sAcc[4][64][17];   // 17.4 KB
  __shared__ float sPs[8][2][16];
  __shared__ float sMu[16];
  const int t = threadIdx.x;
  const int lane = t & 63, w = t >> 6;        // w 0..7
  const int r0 = blockIdx.x * 16;
  const int hb = blockIdx.y;                  // head-half: heads [4hb, 4hb+4)
  const int q = lane >> 4, n16 = lane & 15, oct = q & 1;
  const bool qlt2 = (q < 2);
  const int p1 = qlt2 ? 0 : 1, p2 = qlt2 ? 1 : 0, p3 = qlt2 ? 2 : 0;
  const int row = r0 + n16;

  f32x4 acc[4];
#pragma unroll
  for (int h = 0; h < 4; ++h) acc[h] = (f32x4){0.f, 0.f, 0.f, 0.f};
  float ps = 0.f;

#pragma unroll 4
  for (int dg2 = 0; dg2 < 8; ++dg2) {
    const int dg = w * 8 + dg2;
    const int dq = dg * 16 + oct * 8;
    float4 xa = *(const float4*)(x + (size_t)row * 1024 + dq);
    float4 xb = *(const float4*)(x + (size_t)row * 1024 + dq + 4);
    float xf[8] = {xa.x, xa.y, xa.z, xa.w, xb.x, xb.y, xb.z, xb.w};
    ps += ((xf[0] + xf[1]) + (xf[2] + xf[3])) +
          ((xf[4] + xf[5]) + (xf[6] + xf[7]));
    __attribute__((aligned(16))) unsigned short s1[8], s3[8];
#pragma unroll
    for (int j = 0; j < 8; ++j) {
      unsigned short hh, mm, ll;
      split3(xf[j], hh, mm, ll);
      s1[j] = qlt2 ? hh : mm;
      s3[j] = qlt2 ? hh : ll;
    }
    bf16x8 a1 = *(bf16x8*)s1;
    bf16x8 a3 = *(bf16x8*)s3;
#pragma unroll
    for (int hh = 0; hh < 4; ++hh) {
      const int hg = hb * 4 + hh;
      size_t b0 = (((size_t)(dg * 8 + hg) * 3) * 16 + n16) * 16 + oct * 8;
      bf16x8 b1 = *(const bf16x8*)(wfrag + b0 + p1 * 256);
      bf16x8 b2 = *(const bf16x8*)(wfrag + b0 + p2 * 256);
      bf16x8 b3 = *(const bf16x8*)(wfrag + b0 + p3 * 256);
      acc[hh] = __builtin_amdgcn_mfma_f32_16x16x32_bf16(a1, b1, acc[hh], 0, 0, 0);
      acc[hh] = __builtin_amdgcn_mfma_f32_16x16x32_bf16(a1, b2, acc[hh], 0, 0, 0);
      acc[hh] = __builtin_amdgcn_mfma_f32_16x16x32_bf16(a3, b3, acc[hh], 0, 0, 0);
    }
  }

  // wave-pair reduce: waves 4-7 dump, waves 0-3 add partner's partial.
  if (w >= 4) {
#pragma unroll
    for (int hh = 0; hh < 4; ++hh)
#pragma unroll
      for (int r = 0; r < 4; ++r) sAcc[w - 4][lane][hh * 4 + r] = acc[hh][r];
  }
  if (q < 2) sPs[w][q][n16] = ps;
  __syncthreads();
  if (w < 4) {
#pragma unroll
    for (int hh = 0; hh < 4; ++hh)
#pragma unroll
      for (int r = 0; r < 4; ++r)
        sAcc[w][lane][hh * 4 + r] = acc[hh][r] + sAcc[w][lane][hh * 4 + r];
  }
  if (t < 16) {
    float s = 0.f;
#pragma unroll
    for (int w2 = 0; w2 < 8; ++w2) s += sPs[w2][0][t] + sPs[w2][1][t];
    sMu[t] = s * (1.0f / 1024.0f);
  }
  __syncthreads();

  // epilogue: threads t<256; local head = t>>6, l = t&63, 4 acc regs each.
  if (t < 256) {
    const int l = t & 63, hl = t >> 6;
    const int hg = hb * 4 + hl;
    const int lq = l >> 4, ln = l & 15;
    const float cs = csum[hg * 16 + ln];
#pragma unroll
    for (int r = 0; r < 4; ++r) {
      const int f = hl * 4 + r;
      float v = ((sAcc[0][l][f] + sAcc[1][l][f]) +
                 (sAcc[2][l][f] + sAcc[3][l][f]));
      const int row16 = lq * 4 + r;
      float tv = v - sMu[row16] * cs;
      unsigned short vh, vm, vl;
      split3(tv, vh, vm, vl);
      size_t base = ((size_t)hg * 8192 + r0 + row16) * 16 + ln;
      ph[base] = vh; pm[base] = vm; pl[base] = vl;
    }
  }
}

// ---------------- K4: MFMA argmax partials (LDS-staged codebook) ------------
// Grid (32 rowgroups, 8 heads, 8 code-eighths) x 256 = 2048 blocks (8/CU).
// Per block: the (h,z) cfrag chunk (24KB contiguous) staged once into LDS.
// Wave = 64 rows (4 row-tiles, A-frags in regs). Per-lane codes ascend ->
// strict '>' = first max; shfl_xor(w16) lexicographic; merged in k_amred.
__global__ __launch_bounds__(256) void k_argmax(
    const unsigned short* __restrict__ ph, const unsigned short* __restrict__ pm,
    const unsigned short* __restrict__ pl, const unsigned short* __restrict__ cfrag,
    float* __restrict__ amv, int* __restrict__ ami) {
  __shared__ __align__(16) unsigned short sB[12288];   // 24 KB
  const int t = threadIdx.x;
  const int lane = t & 63, w = t >> 6;
  const int h = blockIdx.y;
  const int z = blockIdx.z;
  const int r0 = blockIdx.x * 256 + w * 64;
  const int q = lane >> 4, n16 = lane & 15;
  const int ehalf = (q & 1) * 8;
  const bool qlt2 = (q < 2);
  const int p1 = qlt2 ? 0 : 1, p2 = qlt2 ? 1 : 0, p3 = qlt2 ? 2 : 0;

  const float* src = (const float*)(cfrag + ((size_t)(h * 128 + z * 16) * 3) * 256);
#pragma unroll
  for (int i = 0; i < 6; ++i)
    stage16(src + ((size_t)((i * 4 + w) * 64) + lane) * 4,
            (float*)sB + (i * 4 + w) * 256);

  const unsigned short* pa1 = qlt2 ? ph : pm;   // A1 = [h|m]
  const unsigned short* pa3 = qlt2 ? ph : pl;   // A3 = [h|l]
  bf16x8 a1[4], a3[4];
#pragma unroll
  for (int rt = 0; rt < 4; ++rt) {
    size_t off = ((size_t)h * 8192 + r0 + rt * 16 + n16) * 16 + ehalf;
    a1[rt] = *(const bf16x8*)(pa1 + off);
    a3[rt] = *(const bf16x8*)(pa3 + off);
  }

  float best[4][4];
  int   bidx[4][4];
#pragma unroll
  for (int rt = 0; rt < 4; ++rt)
#pragma unroll
    for (int r = 0; r < 4; ++r) { best[rt][r] = -3.402823466e38f; bidx[rt][r] = 0; }

  __syncthreads();

  for (int tile = 0; tile < 16; ++tile) {
    const int b0 = tile * 768 + n16 * 16 + ehalf;
    bf16x8 b1 = *(const bf16x8*)(sB + b0 + p1 * 256);
    bf16x8 b2 = *(const bf16x8*)(sB + b0 + p2 * 256);
    bf16x8 b3 = *(const bf16x8*)(sB + b0 + p3 * 256);
    const int code = z * 256 + tile * 16 + n16;
#pragma unroll
    for (int rt = 0; rt < 4; ++rt) {
      f32x4 acc = {0.f, 0.f, 0.f, 0.f};
      acc = __builtin_amdgcn_mfma_f32_16x16x32_bf16(a1[rt], b1, acc, 0, 0, 0);
      acc = __builtin_amdgcn_mfma_f32_16x16x32_bf16(a1[rt], b2, acc, 0, 0, 0);
      acc = __builtin_amdgcn_mfma_f32_16x16x32_bf16(a3[rt], b3, acc, 0, 0, 0);
#pragma unroll
      for (int r = 0; r < 4; ++r)
        if (acc[r] > best[rt][r]) { best[rt][r] = acc[r]; bidx[rt][r] = code; }
    }
  }

#pragma unroll
  for (int off = 8; off >= 1; off >>= 1) {
#pragma unroll
    for (int rt = 0; rt < 4; ++rt)
#pragma unroll
      for (int r = 0; r < 4; ++r) {
        float ov = __shfl_xor(best[rt][r], off, 16);
        int   oi = __shfl_xor(bidx[rt][r], off, 16);
        if (ov > best[rt][r] || (ov == best[rt][r] && oi < bidx[rt][r])) {
          best[rt][r] = ov; bidx[rt][r] = oi;
        }
      }
  }
  if (n16 == 0) {
#pragma unroll
    for (int rt = 0; rt < 4; ++rt)
#pragma unroll
      for (int r = 0; r < 4; ++r) {
        int row = r0 + rt * 16 + q * 4 + r;
        size_t o = (size_t)z * 65536 + (size_t)row * 8 + h;
        amv[o] = best[rt][r]; ami[o] = bidx[rt][r];
      }
  }
}

// ---------------- K5: merge the eight code-eighths --------------------------
__global__ __launch_bounds__(256) void k_amred(const float* __restrict__ amv,
                                               const int* __restrict__ ami,
                                               int* __restrict__ out) {
  int i = blockIdx.x * 256 + threadIdx.x;   // 65536
  float bv = amv[i]; int bi = ami[i];
#pragma unroll
  for (int z = 1; z < 8; ++z) {
    float v = amv[(size_t)z * 65536 + i];
    if (v > bv) { bv = v; bi = ami[(size_t)z * 65536 + i]; }
  }
  out[i] = bi;
}

extern "C" void kernel_launch(void* const* d_in, const int* in_sizes, int n_in,
                              void* d_out, int out_size, void* d_ws, size_t ws_size,
                              hipStream_t stream) {
  (void)in_sizes; (void)n_in; (void)out_size; (void)ws_size;
  const float* x  = (const float*)d_in[0];   // [4,2048,1024]
  const float* rp = (const float*)d_in[1];   // [8,1024,16]
  const float* cb = (const float*)d_in[2];   // [8,2048,16]
  int* out = (int*)d_out;                    // [8192,8] int32

  float* ws = (float*)d_ws;
  float*          csum  = ws;                              // 128
  float*          amv   = ws + 128;                        // 524288
  int*            ami   = (int*)(ws + 524416);             // 524288
  unsigned short* wfrag = (unsigned short*)(ws + 1048704); // 393216 sh
  unsigned short* cfrag = (unsigned short*)(ws + 1245312); // 786432 sh
  unsigned short* ph    = (unsigned short*)(ws + 1638528); // 1048576 sh each
  unsigned short* pm    = (unsigned short*)(ws + 2162816);
  unsigned short* pl    = (unsigned short*)(ws + 2687104); // end ~12.8 MB

  hipLaunchKernelGGL(k_prep,    dim3(136),       dim3(256), 0, stream, cb, rp, cfrag, csum, wfrag);
  hipLaunchKernelGGL(k_proj,    dim3(512, 2),    dim3(512), 0, stream, x, wfrag, csum, ph, pm, pl);
  hipLaunchKernelGGL(k_argmax,  dim3(32, 8, 8),  dim3(256), 0, stream, ph, pm, pl, cfrag, amv, ami);
  hipLaunchKernelGGL(k_amred,   dim3(256),       dim3(256), 0, stream, amv, ami, out);
}

// Round 14
// 144.336 us; speedup vs baseline: 1.0816x; 1.0816x over previous
//
#include <hip/hip_runtime.h>
#include <math.h>

// b=4,n=2048 -> 8192 rows; d=1024; h=8; e=16; cs=2048. Output int32 [8192,8].
// argmax_c q.cbn_c == argmax_c ((x.W - mu*colsum(W)) . cbn_c): LN 1/sigma and
// q-norm are positive per-(row,head) scalars -> cancel. Codebook normalized fp64.
//
// MFMA path (verified R7/R10): fp32 operands split into 3 bf16 parts h,m,l
// (8+8+8 >= 24 mantissa bits; bf16 exp = fp32 -> no subnormal flush).
// v_p*v_c ~= hh + hm+mh + hl+mm+lh via 3 K=32 bf16 MFMAs, quad-packed.
// Frag-major B layouts (R9/R10) keep every wave B-load one dense region.
//
// R14: revert R13 column-split (redundant x work). R12 shape + x staged into
// LDS row-dense (1 segment per global_load_lds inst vs 32 scattered 16B
// segments for the direct loads -> kills TA serialization). x LDS buffer
// reused as the cross-wave reduce buffer after the MFMA loop.

typedef short bf16x8 __attribute__((ext_vector_type(8)));
typedef float f32x4 __attribute__((ext_vector_type(4)));

__device__ __forceinline__ void stage16(const float* g, float* lds_base) {
  __builtin_amdgcn_global_load_lds(
      (const __attribute__((address_space(1))) void*)g,
      (__attribute__((address_space(3))) void*)lds_base, 16, 0, 0);
}

__device__ __forceinline__ unsigned short f2bf(float f) {
  unsigned u = __builtin_bit_cast(unsigned, f);
  unsigned r = (u + 0x7FFFu + ((u >> 16) & 1u)) >> 16;   // RNE
  return (unsigned short)r;
}
__device__ __forceinline__ float bf2f(unsigned short b) {
  return __builtin_bit_cast(float, (unsigned)b << 16);
}
__device__ __forceinline__ void split3(float v, unsigned short& h,
                                       unsigned short& m, unsigned short& l) {
  h = f2bf(v);
  float r = v - bf2f(h);
  m = f2bf(r);
  float r2 = r - bf2f(m);
  l = f2bf(r2);
}

// ---------------- K1: fused prep: cbnorm | colsum | wsplit ------------------
__global__ __launch_bounds__(256) void k_prep(const float* __restrict__ cb,
                                              const float* __restrict__ W,
                                              unsigned short* __restrict__ cfrag,
                                              float* __restrict__ csum,
                                              unsigned short* __restrict__ wfrag) {
  __shared__ float red[16][17];
  const int bid = blockIdx.x;
  const int t = threadIdx.x;
  if (bid < 64) {            // ---- cbnorm (fp64 normalize + bf16 3-split)
    int v = bid * 256 + t;
    int h = v >> 11, c = v & 2047, tl = c >> 4, n = c & 15;
    const float4* p = (const float4*)(cb + (size_t)v * 16);
    float4 q0 = p[0], q1 = p[1], q2 = p[2], q3 = p[3];
    float f[16] = {q0.x,q0.y,q0.z,q0.w, q1.x,q1.y,q1.z,q1.w,
                   q2.x,q2.y,q2.z,q2.w, q3.x,q3.y,q3.z,q3.w};
    double s = 0.0;
#pragma unroll
    for (int i = 0; i < 16; ++i) s += (double)f[i] * (double)f[i];
    double inv = 1.0 / sqrt(s + 1e-12);
    __attribute__((aligned(16))) unsigned short vp[3][16];
#pragma unroll
    for (int i = 0; i < 16; ++i)
      split3((float)((double)f[i] * inv), vp[0][i], vp[1][i], vp[2][i]);
#pragma unroll
    for (int pp = 0; pp < 3; ++pp) {
      size_t base = ((((size_t)h * 128 + tl) * 3 + pp) * 16 + n) * 16;
      ((bf16x8*)(cfrag + base))[0] = ((bf16x8*)vp[pp])[0];
      ((bf16x8*)(cfrag + base))[1] = ((bf16x8*)vp[pp])[1];
    }
  } else if (bid < 72) {     // ---- colsum
    int h = bid - 64;
    int e = t & 15, part = t >> 4;
    const float* base = W + h * 16384 + e;
    float s = 0.f;
    int d0 = part * 64;
    for (int i = 0; i < 64; ++i) s += base[(d0 + i) * 16];
    red[e][part] = s;
    __syncthreads();
    if (t < 16) {
      float tt = 0.f;
#pragma unroll
      for (int p = 0; p < 16; ++p) tt += red[t][p];
      csum[h * 16 + t] = tt;
    }
  } else {                   // ---- wsplit
    int id = (bid - 72) * 256 + t;
    int o = id & 1, n = (id >> 1) & 15, c = (id >> 5) & 7, dg = id >> 8;
    __attribute__((aligned(16))) unsigned short vp[3][8];
#pragma unroll
    for (int j = 0; j < 8; ++j) {
      float v = W[c * 16384 + (dg * 16 + o * 8 + j) * 16 + n];
      split3(v, vp[0][j], vp[1][j], vp[2][j]);
    }
#pragma unroll
    for (int pp = 0; pp < 3; ++pp) {
      size_t base = ((((size_t)dg * 8 + c) * 3 + pp) * 16 + n) * 16 + o * 8;
      *(bf16x8*)(wfrag + base) = *(bf16x8*)vp[pp];
    }
  }
}

// ---------------- K3: fused projection (full K, LDS-staged x) ---------------
// Grid 512 x 512 threads (2 blocks/CU). Block = 16 rows x 128 cols x K=1024;
// wave w covers d-groups [w*8, w*8+8). x staged row-dense into LDS (pitch
// 1028 floats: start-bank spread 8-wide, dup addrs broadcast). After the
// MFMA loop the x buffer is reused as the cross-wave reduce buffer.
__global__ __launch_bounds__(512) void k_proj(const float* __restrict__ x,
                                              const unsigned short* __restrict__ wfrag,
                                              const float* __restrict__ csum,
                                              unsigned short* __restrict__ ph,
                                              unsigned short* __restrict__ pm,
                                              unsigned short* __restrict__ pl) {
  __shared__ __align__(16) float smem[16 * 1028];   // 65.8 KB (x, then sAcc)
  __shared__ float sPs[8][2][16];
  __shared__ float sMu[16];
  const int t = threadIdx.x;
  const int lane = t & 63, w = t >> 6;        // w 0..7
  const int r0 = blockIdx.x * 16;
  const int q = lane >> 4, n16 = lane & 15, oct = q & 1;
  const bool qlt2 = (q < 2);
  const int p1 = qlt2 ? 0 : 1, p2 = qlt2 ? 1 : 0, p3 = qlt2 ? 2 : 0;

  // stage x: wave w stages rows {2w, 2w+1}; each inst = one dense 1KB chunk.
#pragma unroll
  for (int rr = 0; rr < 2; ++rr)
#pragma unroll
    for (int j4 = 0; j4 < 4; ++j4)
      stage16(x + (size_t)(r0 + 2 * w + rr) * 1024 + j4 * 256 + lane * 4,
              smem + (2 * w + rr) * 1028 + j4 * 256);
  __syncthreads();

  f32x4 acc[8];
#pragma unroll
  for (int h = 0; h < 8; ++h) acc[h] = (f32x4){0.f, 0.f, 0.f, 0.f};
  float ps = 0.f;

#pragma unroll 4
  for (int dg2 = 0; dg2 < 8; ++dg2) {
    const int dg = w * 8 + dg2;
    const int dq = dg * 16 + oct * 8;
    float4 xa = *(const float4*)(smem + n16 * 1028 + dq);
    float4 xb = *(const float4*)(smem + n16 * 1028 + dq + 4);
    float xf[8] = {xa.x, xa.y, xa.z, xa.w, xb.x, xb.y, xb.z, xb.w};
    ps += ((xf[0] + xf[1]) + (xf[2] + xf[3])) +
          ((xf[4] + xf[5]) + (xf[6] + xf[7]));
    __attribute__((aligned(16))) unsigned short s1[8], s3[8];
#pragma unroll
    for (int j = 0; j < 8; ++j) {
      unsigned short hh, mm, ll;
      split3(xf[j], hh, mm, ll);
      s1[j] = qlt2 ? hh : mm;
      s3[j] = qlt2 ? hh : ll;
    }
    bf16x8 a1 = *(bf16x8*)s1;
    bf16x8 a3 = *(bf16x8*)s3;
#pragma unroll
    for (int hh = 0; hh < 8; ++hh) {
      size_t b0 = (((size_t)(dg * 8 + hh) * 3) * 16 + n16) * 16 + oct * 8;
      bf16x8 b1 = *(const bf16x8*)(wfrag + b0 + p1 * 256);
      bf16x8 b2 = *(const bf16x8*)(wfrag + b0 + p2 * 256);
      bf16x8 b3 = *(const bf16x8*)(wfrag + b0 + p3 * 256);
      acc[hh] = __builtin_amdgcn_mfma_f32_16x16x32_bf16(a1, b1, acc[hh], 0, 0, 0);
      acc[hh] = __builtin_amdgcn_mfma_f32_16x16x32_bf16(a1, b2, acc[hh], 0, 0, 0);
      acc[hh] = __builtin_amdgcn_mfma_f32_16x16x32_bf16(a3, b3, acc[hh], 0, 0, 0);
    }
  }

  __syncthreads();   // x reads done; smem now reused as reduce buffer
  float* sAcc = smem;   // [4][64][33]

  // wave-pair reduce: waves 4-7 dump, waves 0-3 add partner's partial.
  if (w >= 4) {
#pragma unroll
    for (int hh = 0; hh < 8; ++hh)
#pragma unroll
      for (int r = 0; r < 4; ++r)
        sAcc[((w - 4) * 64 + lane) * 33 + hh * 4 + r] = acc[hh][r];
  }
  if (q < 2) sPs[w][q][n16] = ps;
  __syncthreads();
  if (w < 4) {
#pragma unroll
    for (int hh = 0; hh < 8; ++hh)
#pragma unroll
      for (int r = 0; r < 4; ++r)
        sAcc[(w * 64 + lane) * 33 + hh * 4 + r] =
            acc[hh][r] + sAcc[(w * 64 + lane) * 33 + hh * 4 + r];
  }
  if (t < 16) {
    float s = 0.f;
#pragma unroll
    for (int w2 = 0; w2 < 8; ++w2) s += sPs[w2][0][t] + sPs[w2][1][t];
    sMu[t] = s * (1.0f / 1024.0f);
  }
  __syncthreads();

  // epilogue: thread (head = t>>6, l = t&63) handles 4 acc regs.
  const int l = t & 63, head = t >> 6;
  const int lq = l >> 4, ln = l & 15;
  const float cs = csum[head * 16 + ln];
#pragma unroll
  for (int r = 0; r < 4; ++r) {
    const int f = head * 4 + r;
    float v = ((sAcc[(0 * 64 + l) * 33 + f] + sAcc[(1 * 64 + l) * 33 + f]) +
               (sAcc[(2 * 64 + l) * 33 + f] + sAcc[(3 * 64 + l) * 33 + f]));
    const int row16 = lq * 4 + r;
    float tv = v - sMu[row16] * cs;
    unsigned short vh, vm, vl;
    split3(tv, vh, vm, vl);
    size_t base = ((size_t)head * 8192 + r0 + row16) * 16 + ln;
    ph[base] = vh; pm[base] = vm; pl[base] = vl;
  }
}

// ---------------- K4: MFMA argmax partials (LDS-staged codebook) ------------
// Grid (32 rowgroups, 8 heads, 8 code-eighths) x 256 = 2048 blocks (8/CU).
__global__ __launch_bounds__(256) void k_argmax(
    const unsigned short* __restrict__ ph, const unsigned short* __restrict__ pm,
    const unsigned short* __restrict__ pl, const unsigned short* __restrict__ cfrag,
    float* __restrict__ amv, int* __restrict__ ami) {
  __shared__ __align__(16) unsigned short sB[12288];   // 24 KB
  const int t = threadIdx.x;
  const int lane = t & 63, w = t >> 6;
  const int h = blockIdx.y;
  const int z = blockIdx.z;
  const int r0 = blockIdx.x * 256 + w * 64;
  const int q = lane >> 4, n16 = lane & 15;
  const int ehalf = (q & 1) * 8;
  const bool qlt2 = (q < 2);
  const int p1 = qlt2 ? 0 : 1, p2 = qlt2 ? 1 : 0, p3 = qlt2 ? 2 : 0;

  const float* src = (const float*)(cfrag + ((size_t)(h * 128 + z * 16) * 3) * 256);
#pragma unroll
  for (int i = 0; i < 6; ++i)
    stage16(src + ((size_t)((i * 4 + w) * 64) + lane) * 4,
            (float*)sB + (i * 4 + w) * 256);

  const unsigned short* pa1 = qlt2 ? ph : pm;   // A1 = [h|m]
  const unsigned short* pa3 = qlt2 ? ph : pl;   // A3 = [h|l]
  bf16x8 a1[4], a3[4];
#pragma unroll
  for (int rt = 0; rt < 4; ++rt) {
    size_t off = ((size_t)h * 8192 + r0 + rt * 16 + n16) * 16 + ehalf;
    a1[rt] = *(const bf16x8*)(pa1 + off);
    a3[rt] = *(const bf16x8*)(pa3 + off);
  }

  float best[4][4];
  int   bidx[4][4];
#pragma unroll
  for (int rt = 0; rt < 4; ++rt)
#pragma unroll
    for (int r = 0; r < 4; ++r) { best[rt][r] = -3.402823466e38f; bidx[rt][r] = 0; }

  __syncthreads();

  for (int tile = 0; tile < 16; ++tile) {
    const int b0 = tile * 768 + n16 * 16 + ehalf;
    bf16x8 b1 = *(const bf16x8*)(sB + b0 + p1 * 256);
    bf16x8 b2 = *(const bf16x8*)(sB + b0 + p2 * 256);
    bf16x8 b3 = *(const bf16x8*)(sB + b0 + p3 * 256);
    const int code = z * 256 + tile * 16 + n16;
#pragma unroll
    for (int rt = 0; rt < 4; ++rt) {
      f32x4 acc = {0.f, 0.f, 0.f, 0.f};
      acc = __builtin_amdgcn_mfma_f32_16x16x32_bf16(a1[rt], b1, acc, 0, 0, 0);
      acc = __builtin_amdgcn_mfma_f32_16x16x32_bf16(a1[rt], b2, acc, 0, 0, 0);
      acc = __builtin_amdgcn_mfma_f32_16x16x32_bf16(a3[rt], b3, acc, 0, 0, 0);
#pragma unroll
      for (int r = 0; r < 4; ++r)
        if (acc[r] > best[rt][r]) { best[rt][r] = acc[r]; bidx[rt][r] = code; }
    }
  }

#pragma unroll
  for (int off = 8; off >= 1; off >>= 1) {
#pragma unroll
    for (int rt = 0; rt < 4; ++rt)
#pragma unroll
      for (int r = 0; r < 4; ++r) {
        float ov = __shfl_xor(best[rt][r], off, 16);
        int   oi = __shfl_xor(bidx[rt][r], off, 16);
        if (ov > best[rt][r] || (ov == best[rt][r] && oi < bidx[rt][r])) {
          best[rt][r] = ov; bidx[rt][r] = oi;
        }
      }
  }
  if (n16 == 0) {
#pragma unroll
    for (int rt = 0; rt < 4; ++rt)
#pragma unroll
      for (int r = 0; r < 4; ++r) {
        int row = r0 + rt * 16 + q * 4 + r;
        size_t o = (size_t)z * 65536 + (size_t)row * 8 + h;
        amv[o] = best[rt][r]; ami[o] = bidx[rt][r];
      }
  }
}

// ---------------- K5: merge the eight code-eighths --------------------------
__global__ __launch_bounds__(256) void k_amred(const float* __restrict__ amv,
                                               const int* __restrict__ ami,
                                               int* __restrict__ out) {
  int i = blockIdx.x * 256 + threadIdx.x;   // 65536
  float bv = amv[i]; int bi = ami[i];
#pragma unroll
  for (int z = 1; z < 8; ++z) {
    float v = amv[(size_t)z * 65536 + i];
    if (v > bv) { bv = v; bi = ami[(size_t)z * 65536 + i]; }
  }
  out[i] = bi;
}

extern "C" void kernel_launch(void* const* d_in, const int* in_sizes, int n_in,
                              void* d_out, int out_size, void* d_ws, size_t ws_size,
                              hipStream_t stream) {
  (void)in_sizes; (void)n_in; (void)out_size; (void)ws_size;
  const float* x  = (const float*)d_in[0];   // [4,2048,1024]
  const float* rp = (const float*)d_in[1];   // [8,1024,16]
  const float* cb = (const float*)d_in[2];   // [8,2048,16]
  int* out = (int*)d_out;                    // [8192,8] int32

  float* ws = (float*)d_ws;
  float*          csum  = ws;                              // 128
  float*          amv   = ws + 128;                        // 524288
  int*            ami   = (int*)(ws + 524416);             // 524288
  unsigned short* wfrag = (unsigned short*)(ws + 1048704); // 393216 sh
  unsigned short* cfrag = (unsigned short*)(ws + 1245312); // 786432 sh
  unsigned short* ph    = (unsigned short*)(ws + 1638528); // 1048576 sh each
  unsigned short* pm    = (unsigned short*)(ws + 2162816);
  unsigned short* pl    = (unsigned short*)(ws + 2687104); // end ~12.8 MB

  hipLaunchKernelGGL(k_prep,    dim3(136),       dim3(256), 0, stream, cb, rp, cfrag, csum, wfrag);
  hipLaunchKernelGGL(k_proj,    dim3(512),       dim3(512), 0, stream, x, wfrag, csum, ph, pm, pl);
  hipLaunchKernelGGL(k_argmax,  dim3(32, 8, 8),  dim3(256), 0, stream, ph, pm, pl, cfrag, amv, ami);
  hipLaunchKernelGGL(k_amred,   dim3(256),       dim3(256), 0, stream, amv, ami, out);
}